// Round 5
// baseline (160.549 us; speedup 1.0000x reference)
//
#include <hip/hip_runtime.h>
#include <stdint.h>

// Problem constants (fixed by setup_inputs)
#define TOKENS 64
#define IN_F   4096
#define OUT_F  11008
#define RANK   16
#define GS     128
#define NG     32
#define ZCOLS  (OUT_F / 8)
#define LORA_SCALE 2.0f
#define BN 32                 // columns per block

using short8  = __attribute__((ext_vector_type(8))) short;
using float4v = __attribute__((ext_vector_type(4))) float;

// round-to-nearest-even fp32 -> bf16 bits; also returns the rounded-back fp32
static __device__ inline uint16_t f2bf(float f, float* back) {
    uint32_t u = __float_as_uint(f);
    uint32_t r = (u + 0x7FFFu + ((u >> 16) & 1u)) >> 16;
    *back = __uint_as_float(r << 16);
    return (uint16_t)r;
}

// ---------------------------------------------------------------------------
// K1: per token t (64 blocks):
//   xb[t][:]    = bf16(x[t][:])
//   xsumT[g][t] = sum over group g of bf16-rounded x   (for GPTQ zero fold)
//   midT[j][t]  = sum_k x[t][k] * lora_A[j][k]         (fp32 LoRA mid)
// ---------------------------------------------------------------------------
__global__ __launch_bounds__(256) void prep_kernel(
        const float* __restrict__ x,
        const float* __restrict__ loraA,
        uint16_t* __restrict__ xb,
        float* __restrict__ xsumT,
        float* __restrict__ midT) {
    __shared__ float redg[256];
    __shared__ float redm[4][16];
    const int t    = blockIdx.x;
    const int tid  = threadIdx.x;
    const int lane = tid & 63;
    const int wv   = tid >> 6;

    float4 xv[4];
    const float4* xp = (const float4*)(x + (size_t)t * IN_F + tid * 16);
    #pragma unroll
    for (int i = 0; i < 4; ++i) xv[i] = xp[i];

    union { uint16_t u[16]; uint4 q[2]; } ob;
    float s = 0.f;
    #pragma unroll
    for (int i = 0; i < 4; ++i) {
        float b;
        ob.u[i * 4 + 0] = f2bf(xv[i].x, &b); s += b;
        ob.u[i * 4 + 1] = f2bf(xv[i].y, &b); s += b;
        ob.u[i * 4 + 2] = f2bf(xv[i].z, &b); s += b;
        ob.u[i * 4 + 3] = f2bf(xv[i].w, &b); s += b;
    }
    uint4* op = (uint4*)(xb + (size_t)t * IN_F + tid * 16);
    op[0] = ob.q[0];
    op[1] = ob.q[1];
    redg[tid] = s;

    // LoRA mid partials: this thread's 16 k-slice against all 16 adapter rows
    float pj[16];
    #pragma unroll
    for (int j = 0; j < 16; ++j) {
        const float4* ap = (const float4*)(loraA + (size_t)j * IN_F + tid * 16);
        float ps = 0.f;
        #pragma unroll
        for (int i = 0; i < 4; ++i) {
            float4 a = ap[i];
            ps += a.x * xv[i].x + a.y * xv[i].y + a.z * xv[i].z + a.w * xv[i].w;
        }
        pj[j] = ps;
    }
    #pragma unroll
    for (int j = 0; j < 16; ++j) {
        #pragma unroll
        for (int off = 32; off; off >>= 1) pj[j] += __shfl_down(pj[j], off);
    }
    if (lane == 0) {
        #pragma unroll
        for (int j = 0; j < 16; ++j) redm[wv][j] = pj[j];
    }
    __syncthreads();
    if (tid < NG) {
        float g = 0.f;
        #pragma unroll
        for (int i = 0; i < 8; ++i) g += redg[tid * 8 + i];
        xsumT[tid * TOKENS + t] = g;
    }
    if (tid < 16)
        midT[tid * TOKENS + t] = redm[0][tid] + redm[1][tid] + redm[2][tid] + redm[3][tid];
}

// ---------------------------------------------------------------------------
// K2: fused GPTQ-dequant GEMM + LoRA epilogue. No split-K, no atomics.
// Block 256 = 4 waves; wave wv = M-tile (16 tokens), covering both 16-col
// N-halves of the block's 32 cols, full K. Per group: stage A chunk
// (64x128 bf16, stride 136) + raw qw ints (16x32, +1 pad) in LDS; dequant via
// the 0x4300 trick (bf16(128+q)); 8 MFMAs per wave per group; per-group fold
// removes (zero+1+128)*xsum and applies scale. Epilogue adds LoRA and stores
// each output exactly once.
// ---------------------------------------------------------------------------
__global__ __launch_bounds__(256) void main_kernel(
        const uint32_t* __restrict__ qw,
        const uint32_t* __restrict__ qz,
        const float* __restrict__ scales,
        const uint16_t* __restrict__ xb,
        const float* __restrict__ xsumT,
        const float* __restrict__ midT,
        const float* __restrict__ loraB,
        float* __restrict__ out) {
    __shared__ uint16_t xs[64 * 136];      // 17408 B
    __shared__ uint32_t bqs[16][BN + 1];   // 2112 B
    __shared__ float    xsl[NG * 64];      // 8192 B, xsum [g][t]
    __shared__ float    mids[16 * 64];     // 4096 B, mid  [j][t]

    const int tid  = threadIdx.x;
    const int m    = tid >> 6;             // wave = M-tile 0..3
    const int lane = tid & 63;
    const int n    = lane & 15;
    const int quad = lane >> 4;
    const int col0 = blockIdx.x * BN;

    // stage xsum (2048 f) + mid (1024 f); visible after first barrier
    #pragma unroll
    for (int i = 0; i < 8; ++i) xsl[i * 256 + tid] = xsumT[i * 256 + tid];
    #pragma unroll
    for (int i = 0; i < 4; ++i) mids[i * 256 + tid] = midT[i * 256 + tid];

    const int sc16 = tid & 15;        // A-staging column (x8 bf16)
    const int qr   = tid >> 4;        // bq staging row 0..15
    const int qc   = (tid & 15) * 2;  // bq staging col (pair)

    float4v acc[2];
    acc[0] = (float4v){0.f, 0.f, 0.f, 0.f};
    acc[1] = (float4v){0.f, 0.f, 0.f, 0.f};

    #pragma unroll 1
    for (int g = 0; g < NG; ++g) {
        // per-group scalars issued early; latency hidden by staging + MFMA
        const float    scl0 = scales[(size_t)g * OUT_F + col0 + n];
        const float    scl1 = scales[(size_t)g * OUT_F + col0 + 16 + n];
        const uint32_t zq0  = qz[(size_t)g * ZCOLS + ((col0 + n) >> 3)];
        const uint32_t zq1  = qz[(size_t)g * ZCOLS + ((col0 + 16 + n) >> 3)];

        uint4 u[4];
        #pragma unroll
        for (int i = 0; i < 4; ++i) {
            int trow = (i * 256 + tid) >> 4;
            u[i] = *(const uint4*)(xb + (size_t)trow * IN_F + g * GS + sc16 * 8);
        }
        uint2 bq = *(const uint2*)(qw + (size_t)(g * 16 + qr) * OUT_F + col0 + qc);

        __syncthreads();   // previous iteration's readers done
        #pragma unroll
        for (int i = 0; i < 4; ++i) {
            int trow = (i * 256 + tid) >> 4;
            *(uint4*)(xs + trow * 136 + sc16 * 8) = u[i];
        }
        bqs[qr][qc]     = bq.x;
        bqs[qr][qc + 1] = bq.y;
        __syncthreads();

        float4v accg[2];
        accg[0] = (float4v){0.f, 0.f, 0.f, 0.f};
        accg[1] = (float4v){0.f, 0.f, 0.f, 0.f};
        #pragma unroll
        for (int ks = 0; ks < 4; ++ks) {
            short8 af = *(const short8*)(xs + (m * 16 + n) * 136 + ks * 32 + quad * 8);
            #pragma unroll
            for (int nh = 0; nh < 2; ++nh) {
                uint32_t q  = bqs[ks * 4 + quad][nh * 16 + n];
                uint32_t lo = q & 0x0F0F0F0Fu;
                uint32_t hi = (q >> 4) & 0x0F0F0F0Fu;
                union { uint32_t u32[4]; short8 s8; } bf;
                #pragma unroll
                for (int i = 0; i < 4; ++i)
                    bf.u32[i] = __builtin_amdgcn_perm(hi, lo, 0x0C040C00u + i * 0x00010001u)
                                | 0x43004300u;
                accg[nh] = __builtin_amdgcn_mfma_f32_16x16x32_bf16(af, bf.s8, accg[nh], 0, 0, 0);
            }
        }

        // fold group: acc += scl * (accg - (z + 1 + 128) * xsum)
        const float4v xv = *(const float4v*)&xsl[g * 64 + m * 16 + quad * 4];
        const float zoff0 = (float)(((zq0 >> (((col0 + n) & 7) * 4)) & 0xFu) + 129u);
        const float zoff1 = (float)(((zq1 >> (((col0 + 16 + n) & 7) * 4)) & 0xFu) + 129u);
        #pragma unroll
        for (int r = 0; r < 4; ++r) {
            acc[0][r] = fmaf(scl0, fmaf(-zoff0, xv[r], accg[0][r]), acc[0][r]);
            acc[1][r] = fmaf(scl1, fmaf(-zoff1, xv[r], accg[1][r]), acc[1][r]);
        }
    }

    // LoRA epilogue: out = acc + 2 * (mid @ loraB^T)
    #pragma unroll
    for (int nh = 0; nh < 2; ++nh) {
        const int col = col0 + nh * 16 + n;
        float4 lb[4];
        const float4* lbp = (const float4*)(loraB + (size_t)col * RANK);
        #pragma unroll
        for (int i = 0; i < 4; ++i) lb[i] = lbp[i];
        float4v ls = (float4v){0.f, 0.f, 0.f, 0.f};
        #pragma unroll
        for (int j = 0; j < 16; ++j) {
            const float lbj = ((const float*)lb)[j];
            const float4v mv = *(const float4v*)&mids[j * 64 + m * 16 + quad * 4];
            #pragma unroll
            for (int r = 0; r < 4; ++r) ls[r] = fmaf(mv[r], lbj, ls[r]);
        }
        #pragma unroll
        for (int r = 0; r < 4; ++r) {
            const int t = m * 16 + quad * 4 + r;
            out[(size_t)t * OUT_F + col] = acc[nh][r] + LORA_SCALE * ls[r];
        }
    }
}

// ---------------------------------------------------------------------------
extern "C" void kernel_launch(void* const* d_in, const int* in_sizes, int n_in,
                              void* d_out, int out_size, void* d_ws, size_t ws_size,
                              hipStream_t stream) {
    const float*    x      = (const float*)d_in[0];
    const uint32_t* qw     = (const uint32_t*)d_in[1];
    const uint32_t* qz     = (const uint32_t*)d_in[2];
    const float*    scales = (const float*)d_in[3];
    const float*    loraA  = (const float*)d_in[4];
    const float*    loraB  = (const float*)d_in[5];
    float* out = (float*)d_out;

    // ws layout: xb bf16 [64][4096] (512 KB) | xsumT [32][64] | midT [16][64]
    uint16_t* xb    = (uint16_t*)d_ws;
    float*    xsumT = (float*)((char*)d_ws + (size_t)TOKENS * IN_F * 2);
    float*    midT  = xsumT + NG * TOKENS;

    prep_kernel<<<TOKENS, 256, 0, stream>>>(x, loraA, xb, xsumT, midT);
    main_kernel<<<OUT_F / BN, 256, 0, stream>>>(qw, qz, scales, xb, xsumT, midT, loraB, out);
}

// Round 6
// 108.913 us; speedup vs baseline: 1.4741x; 1.4741x over previous
//
#include <hip/hip_runtime.h>
#include <stdint.h>

// Problem constants (fixed by setup_inputs)
#define TOKENS 64
#define IN_F   4096
#define OUT_F  11008
#define RANK   16
#define GS     128
#define NG     32
#define ZCOLS  (OUT_F / 8)
#define LORA_SCALE 2.0f
#define BN 32                 // columns per block

using short8  = __attribute__((ext_vector_type(8))) short;
using float4v = __attribute__((ext_vector_type(4))) float;

// round-to-nearest-even fp32 -> bf16 bits; also returns the rounded-back fp32
static __device__ inline uint16_t f2bf(float f, float* back) {
    uint32_t u = __float_as_uint(f);
    uint32_t r = (u + 0x7FFFu + ((u >> 16) & 1u)) >> 16;
    *back = __uint_as_float(r << 16);
    return (uint16_t)r;
}

// ---------------------------------------------------------------------------
// K1: per token t (64 blocks):
//   xf (MFMA-fragment order) = bf16(x)   — xf4[(m*128 + kchunk)*64 + quad*16 + n]
//     holds token (m*16+n), k in [kchunk*32 + quad*8, +8): one uint4 = 8 bf16.
//     A wave's A-fragment load in K2 is then a single coalesced 16 B/lane read.
//   xsumT[g][t] = sum over group g of bf16-rounded x   (GPTQ zero fold)
//   midT[j][t]  = sum_k x[t][k] * lora_A[j][k]         (fp32 LoRA mid)
// ---------------------------------------------------------------------------
__global__ __launch_bounds__(256) void prep_kernel(
        const float* __restrict__ x,
        const float* __restrict__ loraA,
        uint4* __restrict__ xf4,
        float* __restrict__ xsumT,
        float* __restrict__ midT) {
    __shared__ float redg[256];
    __shared__ float redm[4][16];
    const int t    = blockIdx.x;
    const int tid  = threadIdx.x;
    const int lane = tid & 63;
    const int wv   = tid >> 6;

    float4 xv[4];
    const float4* xp = (const float4*)(x + (size_t)t * IN_F + tid * 16);
    #pragma unroll
    for (int i = 0; i < 4; ++i) xv[i] = xp[i];

    union { uint16_t u[16]; uint4 q[2]; } ob;
    float s = 0.f;
    #pragma unroll
    for (int i = 0; i < 4; ++i) {
        float b;
        ob.u[i * 4 + 0] = f2bf(xv[i].x, &b); s += b;
        ob.u[i * 4 + 1] = f2bf(xv[i].y, &b); s += b;
        ob.u[i * 4 + 2] = f2bf(xv[i].z, &b); s += b;
        ob.u[i * 4 + 3] = f2bf(xv[i].w, &b); s += b;
    }
    // scatter into fragment order: this thread covers kchunk = tid/2,
    // quads (tid*2+i)&3 for i=0,1
    {
        const int mm = t >> 4, nn = t & 15;
        const int kchunk = tid >> 1;
        #pragma unroll
        for (int i = 0; i < 2; ++i) {
            const int qd = (tid * 2 + i) & 3;
            xf4[(size_t)((mm * 128 + kchunk) * 64 + qd * 16 + nn)] = ob.q[i];
        }
    }
    redg[tid] = s;

    // LoRA mid partials: this thread's 16 k-slice against all 16 adapter rows
    float pj[16];
    #pragma unroll
    for (int j = 0; j < 16; ++j) {
        const float4* ap = (const float4*)(loraA + (size_t)j * IN_F + tid * 16);
        float ps = 0.f;
        #pragma unroll
        for (int i = 0; i < 4; ++i) {
            float4 a = ap[i];
            ps += a.x * xv[i].x + a.y * xv[i].y + a.z * xv[i].z + a.w * xv[i].w;
        }
        pj[j] = ps;
    }
    #pragma unroll
    for (int j = 0; j < 16; ++j) {
        #pragma unroll
        for (int off = 32; off; off >>= 1) pj[j] += __shfl_down(pj[j], off);
    }
    if (lane == 0) {
        #pragma unroll
        for (int j = 0; j < 16; ++j) redm[wv][j] = pj[j];
    }
    __syncthreads();
    if (tid < NG) {
        float g = 0.f;
        #pragma unroll
        for (int i = 0; i < 8; ++i) g += redg[tid * 8 + i];
        xsumT[tid * TOKENS + t] = g;
    }
    if (tid < 16)
        midT[tid * TOKENS + t] = redm[0][tid] + redm[1][tid] + redm[2][tid] + redm[3][tid];
}

// ---------------------------------------------------------------------------
// K2: fused GPTQ-dequant GEMM + LoRA epilogue.
// Barrier-free K-loop (only one __syncthreads at start, for xsum/mid LDS).
// Block 256 = 4 waves; wave = M-tile (16 tokens) x 32 cols, full K.
// A-fragments read directly from xf (fragment-ordered, coalesced, L2-hot);
// B read directly from qw; 2-deep manual software pipeline hides L2/HBM
// latency with ~12 loads in flight per wave. Dequant via 0x4300 trick
// (bf16(128+q)); per-group fold removes (zero+1+128)*xsum and applies scale.
// ---------------------------------------------------------------------------
#define LOAD_GROUP(g, A, B, S0, S1, Z0, Z1) do {                               \
    _Pragma("unroll")                                                          \
    for (int ks = 0; ks < 4; ++ks) A[ks] = xfw[((g) * 4 + ks) * 64];           \
    _Pragma("unroll")                                                          \
    for (int ks = 0; ks < 4; ++ks) {                                           \
        B[ks * 2]     = qwc[(size_t)((g) * 16 + ks * 4 + quad) * OUT_F];       \
        B[ks * 2 + 1] = qwc[(size_t)((g) * 16 + ks * 4 + quad) * OUT_F + 16];  \
    }                                                                          \
    S0 = scales[(size_t)(g) * OUT_F + col0 + n];                               \
    S1 = scales[(size_t)(g) * OUT_F + col0 + 16 + n];                          \
    Z0 = qz[(size_t)(g) * ZCOLS + ((col0 + n) >> 3)];                          \
    Z1 = qz[(size_t)(g) * ZCOLS + ((col0 + 16 + n) >> 3)];                     \
} while (0)

#define COMPUTE_GROUP(g, A, B, S0, S1, Z0, Z1) do {                            \
    float4v accg0 = (float4v){0.f, 0.f, 0.f, 0.f};                             \
    float4v accg1 = (float4v){0.f, 0.f, 0.f, 0.f};                             \
    _Pragma("unroll")                                                          \
    for (int ks = 0; ks < 4; ++ks) {                                           \
        union { uint4 u; short8 s; } afu; afu.u = A[ks];                       \
        _Pragma("unroll")                                                      \
        for (int nh = 0; nh < 2; ++nh) {                                       \
            uint32_t q  = B[ks * 2 + nh];                                      \
            uint32_t lo = q & 0x0F0F0F0Fu;                                     \
            uint32_t hi = (q >> 4) & 0x0F0F0F0Fu;                              \
            union { uint32_t u32[4]; short8 s8; } bf;                          \
            _Pragma("unroll")                                                  \
            for (int i = 0; i < 4; ++i)                                        \
                bf.u32[i] = __builtin_amdgcn_perm(hi, lo,                      \
                                0x0C040C00u + i * 0x00010001u) | 0x43004300u;  \
            if (nh == 0)                                                       \
                accg0 = __builtin_amdgcn_mfma_f32_16x16x32_bf16(afu.s, bf.s8,  \
                                                                accg0, 0, 0, 0);\
            else                                                               \
                accg1 = __builtin_amdgcn_mfma_f32_16x16x32_bf16(afu.s, bf.s8,  \
                                                                accg1, 0, 0, 0);\
        }                                                                      \
    }                                                                          \
    const float zoff0 = (float)(((Z0 >> (((col0 + n) & 7) * 4)) & 0xFu) + 129u);\
    const float zoff1 = (float)(((Z1 >> (((col0 + 16 + n) & 7) * 4)) & 0xFu) + 129u);\
    const float4v xv = *(const float4v*)&xsl[(g) * 64 + m * 16 + quad * 4];    \
    _Pragma("unroll")                                                          \
    for (int r = 0; r < 4; ++r) {                                              \
        acc[0][r] = fmaf(S0, fmaf(-zoff0, xv[r], accg0[r]), acc[0][r]);        \
        acc[1][r] = fmaf(S1, fmaf(-zoff1, xv[r], accg1[r]), acc[1][r]);        \
    }                                                                          \
} while (0)

__global__ __launch_bounds__(256) void main_kernel(
        const uint32_t* __restrict__ qw,
        const uint32_t* __restrict__ qz,
        const float* __restrict__ scales,
        const uint4* __restrict__ xf4,
        const float* __restrict__ xsumT,
        const float* __restrict__ midT,
        const float* __restrict__ loraB,
        float* __restrict__ out) {
    __shared__ float xsl[NG * 64];      // 8 KB, xsum [g][t]
    __shared__ float mids[16 * 64];     // 4 KB, mid  [j][t]

    const int tid  = threadIdx.x;
    const int m    = tid >> 6;             // wave = M-tile 0..3
    const int lane = tid & 63;
    const int n    = lane & 15;
    const int quad = lane >> 4;
    const int col0 = blockIdx.x * BN;

    #pragma unroll
    for (int i = 0; i < 8; ++i) xsl[i * 256 + tid] = xsumT[i * 256 + tid];
    #pragma unroll
    for (int i = 0; i < 4; ++i) mids[i * 256 + tid] = midT[i * 256 + tid];
    __syncthreads();   // the only block-wide barrier

    const uint4*    xfw = xf4 + (size_t)m * 128 * 64 + lane;
    const uint32_t* qwc = qw + col0 + n;

    float4v acc[2];
    acc[0] = (float4v){0.f, 0.f, 0.f, 0.f};
    acc[1] = (float4v){0.f, 0.f, 0.f, 0.f};

    uint4 A0[4], A1[4];
    uint32_t B0[8], B1[8];
    float S00, S01, S10, S11;
    uint32_t Z00, Z01, Z10, Z11;

    LOAD_GROUP(0, A0, B0, S00, S01, Z00, Z01);
    #pragma unroll 1
    for (int gp = 0; gp < 16; ++gp) {
        const int g0 = gp * 2;
        LOAD_GROUP(g0 + 1, A1, B1, S10, S11, Z10, Z11);
        COMPUTE_GROUP(g0, A0, B0, S00, S01, Z00, Z01);
        if (gp < 15) LOAD_GROUP(g0 + 2, A0, B0, S00, S01, Z00, Z01);
        COMPUTE_GROUP(g0 + 1, A1, B1, S10, S11, Z10, Z11);
    }

    // LoRA epilogue: out = acc + 2 * (mid @ loraB^T)
    #pragma unroll
    for (int nh = 0; nh < 2; ++nh) {
        const int col = col0 + nh * 16 + n;
        float4 lb[4];
        const float4* lbp = (const float4*)(loraB + (size_t)col * RANK);
        #pragma unroll
        for (int i = 0; i < 4; ++i) lb[i] = lbp[i];
        float4v ls = (float4v){0.f, 0.f, 0.f, 0.f};
        #pragma unroll
        for (int j = 0; j < 16; ++j) {
            const float lbj = ((const float*)lb)[j];
            const float4v mv = *(const float4v*)&mids[j * 64 + m * 16 + quad * 4];
            #pragma unroll
            for (int r = 0; r < 4; ++r) ls[r] = fmaf(mv[r], lbj, ls[r]);
        }
        #pragma unroll
        for (int r = 0; r < 4; ++r) {
            const int t = m * 16 + quad * 4 + r;
            out[(size_t)t * OUT_F + col] = acc[nh][r] + LORA_SCALE * ls[r];
        }
    }
}

// ---------------------------------------------------------------------------
extern "C" void kernel_launch(void* const* d_in, const int* in_sizes, int n_in,
                              void* d_out, int out_size, void* d_ws, size_t ws_size,
                              hipStream_t stream) {
    const float*    x      = (const float*)d_in[0];
    const uint32_t* qw     = (const uint32_t*)d_in[1];
    const uint32_t* qz     = (const uint32_t*)d_in[2];
    const float*    scales = (const float*)d_in[3];
    const float*    loraA  = (const float*)d_in[4];
    const float*    loraB  = (const float*)d_in[5];
    float* out = (float*)d_out;

    // ws layout: xf bf16-fragments [4][128][64] uint4 (512 KB) | xsumT | midT
    uint4* xf4   = (uint4*)d_ws;
    float* xsumT = (float*)((char*)d_ws + (size_t)TOKENS * IN_F * 2);
    float* midT  = xsumT + NG * TOKENS;

    prep_kernel<<<TOKENS, 256, 0, stream>>>(x, loraA, xf4, xsumT, midT);
    main_kernel<<<OUT_F / BN, 256, 0, stream>>>(qw, qz, scales, xf4, xsumT, midT, loraB, out);
}